// Round 12
// baseline (4197.235 us; speedup 1.0000x reference)
//
#include <hip/hip_runtime.h>

#define T_LEN 1024
#define DIN   512
#define HID   1024
#define GRID  128    // 64 WGs/layer: 32 col-slices x 2 batch-halves
#define RING  8
#define GUARD_CAP (1u << 18)   // poll watchdog: decay to fast wrong-answer, never hang

typedef __attribute__((ext_vector_type(8))) short short8;  // 8 x bf16 bits
typedef __attribute__((ext_vector_type(4))) float f4;
typedef unsigned long long u64;
typedef unsigned short u16;

#define LD_AG(p)    __hip_atomic_load((p),  __ATOMIC_RELAXED, __HIP_MEMORY_SCOPE_AGENT)
#define ST_AG(p, v) __hip_atomic_store((p), (v), __ATOMIC_RELAXED, __HIP_MEMORY_SCOPE_AGENT)

// L3-coherent 16B ops (proven round-6/10 path)
#define GLDC(dst, ptr) \
  asm volatile("global_load_dwordx4 %0, %1, off sc0 sc1" : "=v"(dst) : "v"(ptr))
#define GSTC(ptr, val) \
  asm volatile("global_store_dwordx4 %0, %1, off sc0 sc1" :: "v"(ptr), "v"(val) : "memory")
// plain cached 16B load (read-only x)
#define GLDP(dst, ptr) \
  asm volatile("global_load_dwordx4 %0, %1, off" : "=v"(dst) : "v"(ptr))

template<int N> __device__ __forceinline__ void waitv() {
  asm volatile("s_waitcnt vmcnt(%0)" :: "i"(N) : "memory");
  __builtin_amdgcn_sched_barrier(0);   // rule #18
}

__device__ __forceinline__ u16 f2bf(float f) {
  union { float f; unsigned u; } v; v.f = f;
  return (u16)((v.u + 0x7FFFu + ((v.u >> 16) & 1u)) >> 16);  // RNE
}
__device__ __forceinline__ float bf2f(u16 b) {
  union { unsigned u; float f; } v; v.u = ((unsigned)b) << 16; return v.f;
}
__device__ __forceinline__ short8 cvt8(f4 a, f4 b) {
  short8 r;
  r[0]=(short)f2bf(a[0]); r[1]=(short)f2bf(a[1]); r[2]=(short)f2bf(a[2]); r[3]=(short)f2bf(a[3]);
  r[4]=(short)f2bf(b[0]); r[5]=(short)f2bf(b[1]); r[6]=(short)f2bf(b[2]); r[7]=(short)f2bf(b[3]);
  return r;
}
__device__ __forceinline__ void cvt8hl(f4 a, f4 b, short8& hi, short8& lo) {
  hi = cvt8(a, b);
  f4 ra, rb;
#pragma unroll
  for (int j = 0; j < 4; ++j) {
    ra[j] = a[j] - bf2f((u16)hi[j]);
    rb[j] = b[j] - bf2f((u16)hi[4 + j]);
  }
  lo = cvt8(ra, rb);
}
__device__ __forceinline__ float tanh_fast(float x) {
  float e = __expf(2.f * x);
  return 1.f - 2.f / (e + 1.f);
}
__device__ __forceinline__ f4 mfma16(short8 a, short8 b, f4 c) {
  return __builtin_amdgcn_mfma_f32_16x16x32_bf16(a, b, c, 0, 0, 0);
}
__device__ __forceinline__ f4 fma3(short8 ah, short8 al, short8 bh, short8 bl, f4 c) {
  c = mfma16(ah, bh, c);
  c = mfma16(al, bh, c);
  c = mfma16(ah, bl, c);
  return c;
}

// zero parity-0 of both rings + 128 dense flags
__global__ void prep_kernel(unsigned int* __restrict__ z) {
  int i = blockIdx.x * 256 + threadIdx.x;          // 128 blocks -> 32768 threads
  z[i] = 0u;                                       // h0 parity 0 (128 KB: hi+lo planes)
  z[262144 + i] = 0u;                              // h1 parity 0
  if (i < 128) z[524288 + i] = 0u;                 // flags (512 B, dense)
}

// Persistent fused 2-layer RNN, batch-split — ROUND-10 PROTOCOL (proven) with:
//  (a) dense 4B flags (same 128 slots, poll gather <=8 lines vs 64),
//  (b) flag publish moved BEFORE the output stores (outy drain off critical path).
// Global WG id g: layer=g>>6; wg=g&63, bh=(wg>>5)&1, cs=wg&31. fid = global id.
// Gating (identical to round 10): lanes<32 poll ALL 32 own-layer same-bh peers thr=t;
// L0 lanes>=32 poll 32 L1 same-bh thr=t-4; L1 lanes>=32 poll 32 L0 same-bh thr=t+1.
template<int L>
__device__ __forceinline__ void rnn_body(
    const float* __restrict__ x,
    const float* __restrict__ Wih, const float* __restrict__ Whh,
    const float* __restrict__ bias_i, const float* __restrict__ bias_h,
    char* __restrict__ h0ring, char* __restrict__ h1ring,
    int* __restrict__ gfl,
    float* __restrict__ outy, float* __restrict__ outh,
    float* red, u16* trh, u16* trl, short8* wlo, int wg) {
  const int fid = L * 64 + wg;        // global flag slot
  const int cs = wg & 31;
  const int bh = (wg >> 5) & 1;
  const int i_base = cs * 32;
  const int tid  = threadIdx.x;
  const int wv   = tid >> 6;
  const int lane = tid & 63;
  const int l15  = lane & 15;
  const int kb   = lane >> 4;

  constexpr int K1   = L ? HID : DIN;
  constexpr int NPRE = L ? 8 : 4;
  char* ringW = L ? h1ring : h0ring;

  // ---- hoist weights: hi -> regs, lo -> LDS (slots: pre kk*2+nf, rec 16+kk*2+nf) ----
  short8 bpre[NPRE][2], brhi[8][2];
#pragma unroll
  for (int kk = 0; kk < NPRE; ++kk)
#pragma unroll
    for (int nf = 0; nf < 2; ++nf) {
      int k = wv * (K1 / 4) + kk * 32 + kb * 8;
      const float* sp = Wih + (size_t)(i_base + nf * 16 + l15) * K1 + k;
      short8 lo; cvt8hl(*(const f4*)sp, *(const f4*)(sp + 4), bpre[kk][nf], lo);
      wlo[(wv * 32 + kk * 2 + nf) * 64 + lane] = lo;
    }
#pragma unroll
  for (int kk = 0; kk < 8; ++kk)
#pragma unroll
    for (int nf = 0; nf < 2; ++nf) {
      int k = wv * 256 + kk * 32 + kb * 8;
      const float* sp = Whh + (size_t)(i_base + nf * 16 + l15) * HID + k;
      short8 lo; cvt8hl(*(const f4*)sp, *(const f4*)(sp + 4), brhi[kk][nf], lo);
      wlo[(wv * 32 + 16 + kk * 2 + nf) * 64 + lane] = lo;
    }
  __syncthreads();

  // epilogue constants (waves 0,1 finalize N-frag wv)
  const int e_i = i_base + (wv & 1) * 16 + l15;
  float biasv = 0.f;
  if (wv < 2) biasv = bias_i[e_i] + bias_h[e_i];
  const int c_col = (wv & 1) * 16 + l15;

  // ---- per-lane dependency mapping (round-10 sets, dense slots) ----
  int fidx, foff;
  if (L == 0) {
    if (lane < 32) { fidx = bh * 32 + lane;             foff = 0;  }
    else           { fidx = 64 + bh * 32 + (lane - 32); foff = -4; }
  } else {
    if (lane < 32) { fidx = 64 + bh * 32 + lane;        foff = 0;  }
    else           { fidx = bh * 32 + (lane - 32);      foff = 1;  }
  }
  const int* flagp = gfl + fidx;

#define ISSR(kk) { \
    GLDC(gh[kk], rec + (kk) * 2048); \
    GLDC(gl[kk], rec + (kk) * 2048 + 65536); }
#define ISSP(kk) { GLDC(ph[kk], pre + (kk) * 2048); }
#define MFR(kk, VC) { \
    short8 bl0 = wlo[(wv * 32 + 16 + (kk) * 2 + 0) * 64 + lane]; \
    short8 bl1 = wlo[(wv * 32 + 16 + (kk) * 2 + 1) * 64 + lane]; \
    waitv<VC>(); \
    acc0 = fma3(gh[kk], gl[kk], brhi[kk][0], bl0, acc0); \
    acc1 = fma3(gh[kk], gl[kk], brhi[kk][1], bl1, acc1); }
#define MFP(kk, VC) { \
    short8 bl0 = wlo[(wv * 32 + (kk) * 2 + 0) * 64 + lane]; \
    short8 bl1 = wlo[(wv * 32 + (kk) * 2 + 1) * 64 + lane]; \
    waitv<VC>(); \
    acc0 = mfma16(ph[kk], bpre[kk][0], acc0); \
    acc0 = mfma16(ph[kk], bl0, acc0); \
    acc1 = mfma16(ph[kk], bpre[kk][1], acc1); \
    acc1 = mfma16(ph[kk], bl1, acc1); }

  for (int t = 0; t < T_LEN; ++t) {
    // ---- L0: issue x loads before the poll (poll's flag-load wait drains them) ----
    f4 xa[8];
    if constexpr (L == 0) {
      const float* xr = x + ((size_t)(bh * 16 + l15) * T_LEN + t) * DIN;
#pragma unroll
      for (int kk = 0; kk < 4; ++kk) {
        int k = wv * 128 + kk * 32 + kb * 8;
        GLDP(xa[kk * 2],     (xr + k));
        GLDP(xa[kk * 2 + 1], (xr + k + 4));
      }
    }

    // ---- wave-lockstep guarded poll (each lane one dep) ----
    {
      const int thr = t + foff;
      unsigned gd = 0;
      while (LD_AG(flagp) < thr) {
        if (++gd > GUARD_CAP) break;
        __builtin_amdgcn_s_sleep(1);
      }
    }
    __builtin_amdgcn_sched_barrier(0);

    const char* rec = ringW + (size_t)(t & (RING - 1)) * 131072
                      + wv * 16384 + bh * 1024 + lane * 16;
    f4 acc0 = {0.f,0.f,0.f,0.f}, acc1 = acc0;
    short8 gh[8], gl[8];

    if constexpr (L == 0) {
      // issue the WHOLE step's rec loads up front (16 in flight)
      ISSR(0); ISSR(1); ISSR(2); ISSR(3); ISSR(4); ISSR(5); ISSR(6); ISSR(7);
      // x-block (data already drained by the poll) overlaps the rec flight
#pragma unroll
      for (int kk = 0; kk < 4; ++kk) {
        short8 a0h, a0l;
        cvt8hl(xa[kk * 2], xa[kk * 2 + 1], a0h, a0l);
        short8 bl0 = wlo[(wv * 32 + kk * 2 + 0) * 64 + lane];
        short8 bl1 = wlo[(wv * 32 + kk * 2 + 1) * 64 + lane];
        acc0 = fma3(a0h, a0l, bpre[kk][0], bl0, acc0);
        acc1 = fma3(a0h, a0l, bpre[kk][1], bl1, acc1);
      }
      MFR(0, 14); MFR(1, 12); MFR(2, 10); MFR(3, 8);
      MFR(4, 6);  MFR(5, 4);  MFR(6, 2);  MFR(7, 0);
    } else {
      const char* pre = h0ring + (size_t)((t + 1) & (RING - 1)) * 131072
                        + wv * 16384 + bh * 1024 + lane * 16;
      short8 ph[8];
      // 24 loads in flight: 16 rec + 8 pre (hi-only y0)
      ISSR(0); ISSR(1); ISSR(2); ISSR(3); ISSR(4); ISSR(5); ISSR(6); ISSR(7);
      ISSP(0); ISSP(1); ISSP(2); ISSP(3); ISSP(4); ISSP(5); ISSP(6); ISSP(7);
      MFR(0, 22); MFR(1, 20); MFR(2, 18); MFR(3, 16);
      MFR(4, 14); MFR(5, 12); MFR(6, 10); MFR(7, 8);
      MFP(0, 7); MFP(1, 6); MFP(2, 5); MFP(3, 4);
      MFP(4, 3); MFP(5, 2); MFP(6, 1); MFP(7, 0);
    }

    // ---- cross-wave K reduction via LDS (8 KB) ----
    *(f4*)&red[((wv * 2 + 0) * 64 + lane) * 4] = acc0;
    *(f4*)&red[((wv * 2 + 1) * 64 + lane) * 4] = acc1;
    __syncthreads();

    float vkeep[4];
    if (wv < 2) {
      f4 tot = *(const f4*)&red[((0 * 2 + wv) * 64 + lane) * 4];
      tot += *(const f4*)&red[((1 * 2 + wv) * 64 + lane) * 4];
      tot += *(const f4*)&red[((2 * 2 + wv) * 64 + lane) * 4];
      tot += *(const f4*)&red[((3 * 2 + wv) * 64 + lane) * 4];
      // C/D layout: col = lane&15, row = (lane>>4)*4 + reg  [m89]
#pragma unroll
      for (int rr = 0; rr < 4; ++rr) {
        const int bl = kb * 4 + rr;               // row 0..15 of this batch-half
        float v = tanh_fast(tot[rr] + biasv);
        vkeep[rr] = v;
        u16 hi = f2bf(v);
        u16 lo = f2bf(v - bf2f(hi));
        trh[bl * 36 + c_col] = hi;
        trl[bl * 36 + c_col] = lo;
      }
    }
    __syncthreads();   // tile ready

    // ---- waves 2,3: coalesced ring stores (hi / lo plane) ----
    if (wv >= 2) {
      const u16* srow = (wv == 2) ? &trh[(lane & 15) * 36 + (lane >> 4) * 8]
                                  : &trl[(lane & 15) * 36 + (lane >> 4) * 8];
      union { u64 q[2]; short8 s; } uu;
      uu.q[0] = ((const u64*)srow)[0];
      uu.q[1] = ((const u64*)srow)[1];
      char* d = ringW + (size_t)((t + 1) & (RING - 1)) * 131072
                + (wv == 3 ? 65536 : 0)
                + (size_t)(((cs * 2 + bh) * 64 + lane) * 16);
      GSTC(d, uu.s);
    }
    waitv<0>();        // waves 2/3 drain ring stores; waves 0/1 immediate
    __syncthreads();
    if (tid == 0) ST_AG(gfl + fid, t + 1);   // publish BEFORE output stores

    // ---- outputs after publish (off the inter-WG critical path;
    //      their drain folds into the next step's poll wait) ----
    if (wv < 2) {
      if constexpr (L == 1) {
#pragma unroll
        for (int rr = 0; rr < 4; ++rr) {
          const int brow = bh * 16 + kb * 4 + rr;
          float vo = __shfl_xor(vkeep[rr], 1, 64);
          if ((l15 & 1) == 0)
            *(float2*)&outy[((size_t)brow * T_LEN + t) * HID + e_i] = make_float2(vkeep[rr], vo);
        }
      }
      if (t == T_LEN - 1) {
#pragma unroll
        for (int rr = 0; rr < 4; ++rr) {
          const int brow = bh * 16 + kb * 4 + rr;
          outh[(size_t)L * 32768 + (size_t)brow * HID + e_i] = vkeep[rr];
        }
      }
    }
    // no end barrier needed: next-step LDS writes (red after poll; tr after next
    // reduction sync) are separated from this step's reads by >=1 barrier above.
  }
#undef ISSR
#undef ISSP
#undef MFR
#undef MFP
}

__global__ __launch_bounds__(256, 1)
void rnn_fused(const float* __restrict__ x,
               const float* __restrict__ Wih0, const float* __restrict__ Whh0,
               const float* __restrict__ bi0,  const float* __restrict__ bh0,
               const float* __restrict__ Wih1, const float* __restrict__ Whh1,
               const float* __restrict__ bi1,  const float* __restrict__ bh1,
               char* __restrict__ h0ring, char* __restrict__ h1ring,
               int* __restrict__ gfl,
               float* __restrict__ outy, float* __restrict__ outh) {
  __shared__ float  red[8 * 64 * 4];       // 8 KB
  __shared__ u16    trh[16 * 36];          // 1.125 KB
  __shared__ u16    trl[16 * 36];
  __shared__ short8 wlo[4 * 32 * 64];      // 128 KB lo-weights
  const int wg = blockIdx.x;
  if (wg < 64)
    rnn_body<0>(x, Wih0, Whh0, bi0, bh0, h0ring, h1ring, gfl, outy, outh,
                red, trh, trl, wlo, wg);
  else
    rnn_body<1>(x, Wih1, Whh1, bi1, bh1, h0ring, h1ring, gfl, outy, outh,
                red, trh, trl, wlo, wg - 64);
}

extern "C" void kernel_launch(void* const* d_in, const int* in_sizes, int n_in,
                              void* d_out, int out_size, void* d_ws, size_t ws_size,
                              hipStream_t stream) {
  const float* x    = (const float*)d_in[0];
  const float* Wih0 = (const float*)d_in[1];
  const float* Whh0 = (const float*)d_in[2];
  const float* bi0  = (const float*)d_in[3];
  const float* bh0  = (const float*)d_in[4];
  const float* Wih1 = (const float*)d_in[5];
  const float* Whh1 = (const float*)d_in[6];
  const float* bi1  = (const float*)d_in[7];
  const float* bh1  = (const float*)d_in[8];

  float* outy = (float*)d_out;
  float* outh = outy + (size_t)32 * 1024 * 1024;   // [2][32][1024] tail

  char* ws = (char*)d_ws;
  char* h0ring = ws;                        // RING x 131072 B (hi plane 64K + lo plane 64K)
  char* h1ring = ws + 1048576;              // 1 MB
  int*  gfl    = (int*)(ws + 2097152);      // 128 dense flags (512 B)

  prep_kernel<<<128, 256, 0, stream>>>((unsigned int*)ws);
  rnn_fused<<<GRID, 256, 0, stream>>>(x, Wih0, Whh0, bi0, bh0,
                                      Wih1, Whh1, bi1, bh1,
                                      h0ring, h1ring, gfl, outy, outh);
}

// Round 13
// 3555.352 us; speedup vs baseline: 1.1805x; 1.1805x over previous
//
#include <hip/hip_runtime.h>

#define T_LEN 1024
#define DIN   512
#define HID   1024
#define GRID  128    // 64 WGs/layer: 32 col-slices x 2 batch-halves
#define RING  8
#define GUARD_CAP (1u << 18)   // poll watchdog: decay to fast wrong-answer, never hang

typedef __attribute__((ext_vector_type(8))) short short8;  // 8 x bf16 bits
typedef __attribute__((ext_vector_type(4))) float f4;
typedef unsigned long long u64;
typedef unsigned short u16;

#define LD_AG(p)    __hip_atomic_load((p),  __ATOMIC_RELAXED, __HIP_MEMORY_SCOPE_AGENT)
#define ST_AG(p, v) __hip_atomic_store((p), (v), __ATOMIC_RELAXED, __HIP_MEMORY_SCOPE_AGENT)

// L3-coherent 16B ops (proven round-6/10 path)
#define GLDC(dst, ptr) \
  asm volatile("global_load_dwordx4 %0, %1, off sc0 sc1" : "=v"(dst) : "v"(ptr))
#define GSTC(ptr, val) \
  asm volatile("global_store_dwordx4 %0, %1, off sc0 sc1" :: "v"(ptr), "v"(val) : "memory")
// plain cached 16B load (read-only x)
#define GLDP(dst, ptr) \
  asm volatile("global_load_dwordx4 %0, %1, off" : "=v"(dst) : "v"(ptr))

template<int N> __device__ __forceinline__ void waitv() {
  asm volatile("s_waitcnt vmcnt(%0)" :: "i"(N) : "memory");
  __builtin_amdgcn_sched_barrier(0);   // rule #18
}

__device__ __forceinline__ u16 f2bf(float f) {
  union { float f; unsigned u; } v; v.f = f;
  return (u16)((v.u + 0x7FFFu + ((v.u >> 16) & 1u)) >> 16);  // RNE
}
__device__ __forceinline__ float bf2f(u16 b) {
  union { unsigned u; float f; } v; v.u = ((unsigned)b) << 16; return v.f;
}
__device__ __forceinline__ short8 cvt8(f4 a, f4 b) {
  short8 r;
  r[0]=(short)f2bf(a[0]); r[1]=(short)f2bf(a[1]); r[2]=(short)f2bf(a[2]); r[3]=(short)f2bf(a[3]);
  r[4]=(short)f2bf(b[0]); r[5]=(short)f2bf(b[1]); r[6]=(short)f2bf(b[2]); r[7]=(short)f2bf(b[3]);
  return r;
}
__device__ __forceinline__ void cvt8hl(f4 a, f4 b, short8& hi, short8& lo) {
  hi = cvt8(a, b);
  f4 ra, rb;
#pragma unroll
  for (int j = 0; j < 4; ++j) {
    ra[j] = a[j] - bf2f((u16)hi[j]);
    rb[j] = b[j] - bf2f((u16)hi[4 + j]);
  }
  lo = cvt8(ra, rb);
}
__device__ __forceinline__ float tanh_fast(float x) {
  float e = __expf(2.f * x);
  return 1.f - 2.f / (e + 1.f);
}
__device__ __forceinline__ f4 mfma16(short8 a, short8 b, f4 c) {
  return __builtin_amdgcn_mfma_f32_16x16x32_bf16(a, b, c, 0, 0, 0);
}
__device__ __forceinline__ f4 fma3(short8 ah, short8 al, short8 bh, short8 bl, f4 c) {
  c = mfma16(ah, bh, c);
  c = mfma16(al, bh, c);
  c = mfma16(ah, bl, c);
  return c;
}

// zero parity-0 of both rings + 128 line-padded flags (64 B each = 2048 dwords)
__global__ void prep_kernel(unsigned int* __restrict__ z) {
  int i = blockIdx.x * 256 + threadIdx.x;          // 128 blocks -> 32768 threads
  z[i] = 0u;                                       // h0 parity 0 (128 KB: hi+lo planes)
  z[262144 + i] = 0u;                              // h1 parity 0
  if (i < 2048) z[524288 + i] = 0u;                // flags (8 KB, 64B-padded)
}

// Persistent fused 2-layer RNN, batch-split — ROUND-10 PROTOCOL with ONE delta:
// flag publish BEFORE the output stores (outy drain off the inter-WG path).
// Flags are 64B line-padded (round-12's dense packing caused L3 same-line
// write contention: 128 stores/step into 8 lines -> -18%; reverted).
// Global WG id g: layer=g>>6; wg=g&63, bh=(wg>>5)&1, cs=wg&31. fid = global id.
// Gating: lanes<32 poll ALL 32 own-layer same-bh peers thr=t;
// L0 lanes>=32 poll 32 L1 same-bh thr=t-4; L1 lanes>=32 poll 32 L0 same-bh thr=t+1.
template<int L>
__device__ __forceinline__ void rnn_body(
    const float* __restrict__ x,
    const float* __restrict__ Wih, const float* __restrict__ Whh,
    const float* __restrict__ bias_i, const float* __restrict__ bias_h,
    char* __restrict__ h0ring, char* __restrict__ h1ring,
    int* __restrict__ gfl,
    float* __restrict__ outy, float* __restrict__ outh,
    float* red, u16* trh, u16* trl, short8* wlo, int wg) {
  const int fid = L * 64 + wg;        // global flag slot
  const int cs = wg & 31;
  const int bh = (wg >> 5) & 1;
  const int i_base = cs * 32;
  const int tid  = threadIdx.x;
  const int wv   = tid >> 6;
  const int lane = tid & 63;
  const int l15  = lane & 15;
  const int kb   = lane >> 4;

  constexpr int K1   = L ? HID : DIN;
  constexpr int NPRE = L ? 8 : 4;
  char* ringW = L ? h1ring : h0ring;

  // ---- hoist weights: hi -> regs, lo -> LDS (slots: pre kk*2+nf, rec 16+kk*2+nf) ----
  short8 bpre[NPRE][2], brhi[8][2];
#pragma unroll
  for (int kk = 0; kk < NPRE; ++kk)
#pragma unroll
    for (int nf = 0; nf < 2; ++nf) {
      int k = wv * (K1 / 4) + kk * 32 + kb * 8;
      const float* sp = Wih + (size_t)(i_base + nf * 16 + l15) * K1 + k;
      short8 lo; cvt8hl(*(const f4*)sp, *(const f4*)(sp + 4), bpre[kk][nf], lo);
      wlo[(wv * 32 + kk * 2 + nf) * 64 + lane] = lo;
    }
#pragma unroll
  for (int kk = 0; kk < 8; ++kk)
#pragma unroll
    for (int nf = 0; nf < 2; ++nf) {
      int k = wv * 256 + kk * 32 + kb * 8;
      const float* sp = Whh + (size_t)(i_base + nf * 16 + l15) * HID + k;
      short8 lo; cvt8hl(*(const f4*)sp, *(const f4*)(sp + 4), brhi[kk][nf], lo);
      wlo[(wv * 32 + 16 + kk * 2 + nf) * 64 + lane] = lo;
    }
  __syncthreads();

  // epilogue constants (waves 0,1 finalize N-frag wv)
  const int e_i = i_base + (wv & 1) * 16 + l15;
  float biasv = 0.f;
  if (wv < 2) biasv = bias_i[e_i] + bias_h[e_i];
  const int c_col = (wv & 1) * 16 + l15;

  // ---- per-lane dependency mapping (round-10 sets, 64B-padded slots) ----
  int fidx, foff;
  if (L == 0) {
    if (lane < 32) { fidx = bh * 32 + lane;             foff = 0;  }
    else           { fidx = 64 + bh * 32 + (lane - 32); foff = -4; }
  } else {
    if (lane < 32) { fidx = 64 + bh * 32 + lane;        foff = 0;  }
    else           { fidx = bh * 32 + (lane - 32);      foff = 1;  }
  }
  const int* flagp = gfl + fidx * 16;

#define ISSR(kk) { \
    GLDC(gh[kk], rec + (kk) * 2048); \
    GLDC(gl[kk], rec + (kk) * 2048 + 65536); }
#define ISSP(kk) { GLDC(ph[kk], pre + (kk) * 2048); }
#define MFR(kk, VC) { \
    short8 bl0 = wlo[(wv * 32 + 16 + (kk) * 2 + 0) * 64 + lane]; \
    short8 bl1 = wlo[(wv * 32 + 16 + (kk) * 2 + 1) * 64 + lane]; \
    waitv<VC>(); \
    acc0 = fma3(gh[kk], gl[kk], brhi[kk][0], bl0, acc0); \
    acc1 = fma3(gh[kk], gl[kk], brhi[kk][1], bl1, acc1); }
#define MFP(kk, VC) { \
    short8 bl0 = wlo[(wv * 32 + (kk) * 2 + 0) * 64 + lane]; \
    short8 bl1 = wlo[(wv * 32 + (kk) * 2 + 1) * 64 + lane]; \
    waitv<VC>(); \
    acc0 = mfma16(ph[kk], bpre[kk][0], acc0); \
    acc0 = mfma16(ph[kk], bl0, acc0); \
    acc1 = mfma16(ph[kk], bpre[kk][1], acc1); \
    acc1 = mfma16(ph[kk], bl1, acc1); }

  for (int t = 0; t < T_LEN; ++t) {
    // ---- L0: issue x loads before the poll (poll's flag-load wait drains them) ----
    f4 xa[8];
    if constexpr (L == 0) {
      const float* xr = x + ((size_t)(bh * 16 + l15) * T_LEN + t) * DIN;
#pragma unroll
      for (int kk = 0; kk < 4; ++kk) {
        int k = wv * 128 + kk * 32 + kb * 8;
        GLDP(xa[kk * 2],     (xr + k));
        GLDP(xa[kk * 2 + 1], (xr + k + 4));
      }
    }

    // ---- wave-lockstep guarded poll (each lane one dep) ----
    {
      const int thr = t + foff;
      unsigned gd = 0;
      while (LD_AG(flagp) < thr) {
        if (++gd > GUARD_CAP) break;
        __builtin_amdgcn_s_sleep(1);
      }
    }
    __builtin_amdgcn_sched_barrier(0);

    const char* rec = ringW + (size_t)(t & (RING - 1)) * 131072
                      + wv * 16384 + bh * 1024 + lane * 16;
    f4 acc0 = {0.f,0.f,0.f,0.f}, acc1 = acc0;
    short8 gh[8], gl[8];

    if constexpr (L == 0) {
      // issue the WHOLE step's rec loads up front (16 in flight)
      ISSR(0); ISSR(1); ISSR(2); ISSR(3); ISSR(4); ISSR(5); ISSR(6); ISSR(7);
      // x-block (data already drained by the poll) overlaps the rec flight
#pragma unroll
      for (int kk = 0; kk < 4; ++kk) {
        short8 a0h, a0l;
        cvt8hl(xa[kk * 2], xa[kk * 2 + 1], a0h, a0l);
        short8 bl0 = wlo[(wv * 32 + kk * 2 + 0) * 64 + lane];
        short8 bl1 = wlo[(wv * 32 + kk * 2 + 1) * 64 + lane];
        acc0 = fma3(a0h, a0l, bpre[kk][0], bl0, acc0);
        acc1 = fma3(a0h, a0l, bpre[kk][1], bl1, acc1);
      }
      MFR(0, 14); MFR(1, 12); MFR(2, 10); MFR(3, 8);
      MFR(4, 6);  MFR(5, 4);  MFR(6, 2);  MFR(7, 0);
    } else {
      const char* pre = h0ring + (size_t)((t + 1) & (RING - 1)) * 131072
                        + wv * 16384 + bh * 1024 + lane * 16;
      short8 ph[8];
      // 24 loads in flight: 16 rec + 8 pre (hi-only y0)
      ISSR(0); ISSR(1); ISSR(2); ISSR(3); ISSR(4); ISSR(5); ISSR(6); ISSR(7);
      ISSP(0); ISSP(1); ISSP(2); ISSP(3); ISSP(4); ISSP(5); ISSP(6); ISSP(7);
      MFR(0, 22); MFR(1, 20); MFR(2, 18); MFR(3, 16);
      MFR(4, 14); MFR(5, 12); MFR(6, 10); MFR(7, 8);
      MFP(0, 7); MFP(1, 6); MFP(2, 5); MFP(3, 4);
      MFP(4, 3); MFP(5, 2); MFP(6, 1); MFP(7, 0);
    }

    // ---- cross-wave K reduction via LDS (8 KB) ----
    *(f4*)&red[((wv * 2 + 0) * 64 + lane) * 4] = acc0;
    *(f4*)&red[((wv * 2 + 1) * 64 + lane) * 4] = acc1;
    __syncthreads();

    float vkeep[4];
    if (wv < 2) {
      f4 tot = *(const f4*)&red[((0 * 2 + wv) * 64 + lane) * 4];
      tot += *(const f4*)&red[((1 * 2 + wv) * 64 + lane) * 4];
      tot += *(const f4*)&red[((2 * 2 + wv) * 64 + lane) * 4];
      tot += *(const f4*)&red[((3 * 2 + wv) * 64 + lane) * 4];
      // C/D layout: col = lane&15, row = (lane>>4)*4 + reg  [m89]
#pragma unroll
      for (int rr = 0; rr < 4; ++rr) {
        const int bl = kb * 4 + rr;               // row 0..15 of this batch-half
        float v = tanh_fast(tot[rr] + biasv);
        vkeep[rr] = v;
        u16 hi = f2bf(v);
        u16 lo = f2bf(v - bf2f(hi));
        trh[bl * 36 + c_col] = hi;
        trl[bl * 36 + c_col] = lo;
      }
    }
    __syncthreads();   // tile ready

    // ---- waves 2,3: coalesced ring stores (hi / lo plane) ----
    if (wv >= 2) {
      const u16* srow = (wv == 2) ? &trh[(lane & 15) * 36 + (lane >> 4) * 8]
                                  : &trl[(lane & 15) * 36 + (lane >> 4) * 8];
      union { u64 q[2]; short8 s; } uu;
      uu.q[0] = ((const u64*)srow)[0];
      uu.q[1] = ((const u64*)srow)[1];
      char* d = ringW + (size_t)((t + 1) & (RING - 1)) * 131072
                + (wv == 3 ? 65536 : 0)
                + (size_t)(((cs * 2 + bh) * 64 + lane) * 16);
      GSTC(d, uu.s);
    }
    waitv<0>();        // waves 2/3 drain ring stores; waves 0/1 immediate
    __syncthreads();
    if (tid == 0) ST_AG(gfl + fid * 16, t + 1);   // publish BEFORE output stores

    // ---- outputs after publish (off the inter-WG critical path;
    //      their drain folds into the next step's poll wait) ----
    if (wv < 2) {
      if constexpr (L == 1) {
#pragma unroll
        for (int rr = 0; rr < 4; ++rr) {
          const int brow = bh * 16 + kb * 4 + rr;
          float vo = __shfl_xor(vkeep[rr], 1, 64);
          if ((l15 & 1) == 0)
            *(float2*)&outy[((size_t)brow * T_LEN + t) * HID + e_i] = make_float2(vkeep[rr], vo);
        }
      }
      if (t == T_LEN - 1) {
#pragma unroll
        for (int rr = 0; rr < 4; ++rr) {
          const int brow = bh * 16 + kb * 4 + rr;
          outh[(size_t)L * 32768 + (size_t)brow * HID + e_i] = vkeep[rr];
        }
      }
    }
    // no end barrier needed: next-step LDS writes (red after poll; tr after next
    // reduction sync) are separated from this step's reads by >=1 barrier above.
  }
#undef ISSR
#undef ISSP
#undef MFR
#undef MFP
}

__global__ __launch_bounds__(256, 1)
void rnn_fused(const float* __restrict__ x,
               const float* __restrict__ Wih0, const float* __restrict__ Whh0,
               const float* __restrict__ bi0,  const float* __restrict__ bh0,
               const float* __restrict__ Wih1, const float* __restrict__ Whh1,
               const float* __restrict__ bi1,  const float* __restrict__ bh1,
               char* __restrict__ h0ring, char* __restrict__ h1ring,
               int* __restrict__ gfl,
               float* __restrict__ outy, float* __restrict__ outh) {
  __shared__ float  red[8 * 64 * 4];       // 8 KB
  __shared__ u16    trh[16 * 36];          // 1.125 KB
  __shared__ u16    trl[16 * 36];
  __shared__ short8 wlo[4 * 32 * 64];      // 128 KB lo-weights
  const int wg = blockIdx.x;
  if (wg < 64)
    rnn_body<0>(x, Wih0, Whh0, bi0, bh0, h0ring, h1ring, gfl, outy, outh,
                red, trh, trl, wlo, wg);
  else
    rnn_body<1>(x, Wih1, Whh1, bi1, bh1, h0ring, h1ring, gfl, outy, outh,
                red, trh, trl, wlo, wg - 64);
}

extern "C" void kernel_launch(void* const* d_in, const int* in_sizes, int n_in,
                              void* d_out, int out_size, void* d_ws, size_t ws_size,
                              hipStream_t stream) {
  const float* x    = (const float*)d_in[0];
  const float* Wih0 = (const float*)d_in[1];
  const float* Whh0 = (const float*)d_in[2];
  const float* bi0  = (const float*)d_in[3];
  const float* bh0  = (const float*)d_in[4];
  const float* Wih1 = (const float*)d_in[5];
  const float* Whh1 = (const float*)d_in[6];
  const float* bi1  = (const float*)d_in[7];
  const float* bh1  = (const float*)d_in[8];

  float* outy = (float*)d_out;
  float* outh = outy + (size_t)32 * 1024 * 1024;   // [2][32][1024] tail

  char* ws = (char*)d_ws;
  char* h0ring = ws;                        // RING x 131072 B (hi plane 64K + lo plane 64K)
  char* h1ring = ws + 1048576;              // 1 MB
  int*  gfl    = (int*)(ws + 2097152);      // 128 flags x 64 B

  prep_kernel<<<128, 256, 0, stream>>>((unsigned int*)ws);
  rnn_fused<<<GRID, 256, 0, stream>>>(x, Wih0, Whh0, bi0, bh0,
                                      Wih1, Whh1, bi1, bh1,
                                      h0ring, h1ring, gfl, outy, outh);
}

// Round 14
// 2782.195 us; speedup vs baseline: 1.5086x; 1.2779x over previous
//
#include <hip/hip_runtime.h>

#define T_LEN 1024
#define DIN   512
#define HID   1024
#define GRID  128    // 64 WGs/layer: 32 col-slices x 2 batch-halves
#define RING  8
#define GUARD_CAP (1u << 18)   // poll watchdog: decay to fast wrong-answer, never hang

typedef __attribute__((ext_vector_type(8))) _Float16 half8;  // 8 x f16 (4 VGPRs)
typedef __attribute__((ext_vector_type(4))) float f4;
typedef unsigned long long u64;
typedef unsigned short u16;

#define LD_AG(p)    __hip_atomic_load((p),  __ATOMIC_RELAXED, __HIP_MEMORY_SCOPE_AGENT)
#define ST_AG(p, v) __hip_atomic_store((p), (v), __ATOMIC_RELAXED, __HIP_MEMORY_SCOPE_AGENT)

// L3-coherent 16B ops (proven round-6/10/13 path)
#define GLDC(dst, ptr) \
  asm volatile("global_load_dwordx4 %0, %1, off sc0 sc1" : "=v"(dst) : "v"(ptr))
#define GSTC(ptr, val) \
  asm volatile("global_store_dwordx4 %0, %1, off sc0 sc1" :: "v"(ptr), "v"(val) : "memory")
// plain cached 16B load (read-only x)
#define GLDP(dst, ptr) \
  asm volatile("global_load_dwordx4 %0, %1, off" : "=v"(dst) : "v"(ptr))

template<int N> __device__ __forceinline__ void waitv() {
  asm volatile("s_waitcnt vmcnt(%0)" :: "i"(N) : "memory");
  __builtin_amdgcn_sched_barrier(0);   // rule #18
}

__device__ __forceinline__ u16 h_bits(float f) {
  union { _Float16 h; u16 u; } v; v.h = (_Float16)f; return v.u;
}
// f32x8 -> f16x8 (RNE via v_cvt_f16_f32)
__device__ __forceinline__ half8 cvt8h(f4 a, f4 b) {
  half8 r;
#pragma unroll
  for (int j = 0; j < 4; ++j) { r[j] = (_Float16)a[j]; r[4 + j] = (_Float16)b[j]; }
  return r;
}
// f32x8 -> f16 hi + f16 residual (weights: combined error ~2^-22)
__device__ __forceinline__ void cvt8h_hl(f4 a, f4 b, half8& hi, half8& lo) {
  hi = cvt8h(a, b);
#pragma unroll
  for (int j = 0; j < 4; ++j) {
    lo[j]     = (_Float16)(a[j] - (float)hi[j]);
    lo[4 + j] = (_Float16)(b[j] - (float)hi[4 + j]);
  }
}
__device__ __forceinline__ float tanh_fast(float x) {
  float e = __expf(2.f * x);
  return 1.f - 2.f / (e + 1.f);
}
__device__ __forceinline__ f4 mfmah(half8 a, half8 b, f4 c) {
  return __builtin_amdgcn_mfma_f32_16x16x32_f16(a, b, c, 0, 0, 0);
}
// 2-term: a*(bh+bl)
__device__ __forceinline__ f4 fma2(half8 a, half8 bh, half8 bl, f4 c) {
  c = mfmah(a, bh, c);
  c = mfmah(a, bl, c);
  return c;
}

// zero parity-0 of both rings + 128 line-padded flags
// dword offsets: h0 par0 [0,16384) ; h1 par0 at 131072 ; flags at 262144 (2048 dw)
__global__ void prep_kernel(unsigned int* __restrict__ z) {
  int i = blockIdx.x * 256 + threadIdx.x;          // 64 blocks -> 16384 threads
  z[i] = 0u;                                       // h0 parity 0 (64 KB, f16 plane)
  z[131072 + i] = 0u;                              // h1 parity 0
  if (i < 2048) z[262144 + i] = 0u;                // flags (8 KB, 64B-padded)
}

// Persistent fused 2-layer RNN, batch-split — ROUND-13 PROTOCOL, fp16 single-plane h.
// h exchanged as ONE f16 plane (2^-11 quant; replaces bf16 hi/lo pair -> traffic /2;
// y0 mirror eliminated: L1 reads h0's plane directly). Weights f16 hi + f16 residual
// (hi in regs, residual in LDS). Ring parity = 64 KB: 32cs x 2bh blocks of 1 KB.
// Sync identical to round 13: 64B-padded flags, global fid, gating thr {t, t-4, t+1},
// full drain of ring store before publish, outputs after publish.
template<int L>
__device__ __forceinline__ void rnn_body(
    const float* __restrict__ x,
    const float* __restrict__ Wih, const float* __restrict__ Whh,
    const float* __restrict__ bias_i, const float* __restrict__ bias_h,
    char* __restrict__ h0ring, char* __restrict__ h1ring,
    int* __restrict__ gfl,
    float* __restrict__ outy, float* __restrict__ outh,
    float* red, u16* trh, half8* wlo, int wg) {
  const int fid = L * 64 + wg;        // global flag slot
  const int cs = wg & 31;
  const int bh = (wg >> 5) & 1;
  const int i_base = cs * 32;
  const int tid  = threadIdx.x;
  const int wv   = tid >> 6;
  const int lane = tid & 63;
  const int l15  = lane & 15;
  const int kb   = lane >> 4;

  constexpr int K1   = L ? HID : DIN;
  constexpr int NPRE = L ? 8 : 4;
  char* ringW = L ? h1ring : h0ring;

  // ---- hoist weights: f16 hi -> regs, f16 residual -> LDS ----
  half8 bpre[NPRE][2], brhi[8][2];
#pragma unroll
  for (int kk = 0; kk < NPRE; ++kk)
#pragma unroll
    for (int nf = 0; nf < 2; ++nf) {
      int k = wv * (K1 / 4) + kk * 32 + kb * 8;
      const float* sp = Wih + (size_t)(i_base + nf * 16 + l15) * K1 + k;
      half8 lo; cvt8h_hl(*(const f4*)sp, *(const f4*)(sp + 4), bpre[kk][nf], lo);
      wlo[(wv * 32 + kk * 2 + nf) * 64 + lane] = lo;
    }
#pragma unroll
  for (int kk = 0; kk < 8; ++kk)
#pragma unroll
    for (int nf = 0; nf < 2; ++nf) {
      int k = wv * 256 + kk * 32 + kb * 8;
      const float* sp = Whh + (size_t)(i_base + nf * 16 + l15) * HID + k;
      half8 lo; cvt8h_hl(*(const f4*)sp, *(const f4*)(sp + 4), brhi[kk][nf], lo);
      wlo[(wv * 32 + 16 + kk * 2 + nf) * 64 + lane] = lo;
    }
  __syncthreads();

  // epilogue constants (waves 0,1 finalize N-frag wv)
  const int e_i = i_base + (wv & 1) * 16 + l15;
  float biasv = 0.f;
  if (wv < 2) biasv = bias_i[e_i] + bias_h[e_i];
  const int c_col = (wv & 1) * 16 + l15;

  // ---- per-lane dependency mapping (round-13 sets, 64B-padded slots) ----
  int fidx, foff;
  if (L == 0) {
    if (lane < 32) { fidx = bh * 32 + lane;             foff = 0;  }
    else           { fidx = 64 + bh * 32 + (lane - 32); foff = -4; }
  } else {
    if (lane < 32) { fidx = 64 + bh * 32 + lane;        foff = 0;  }
    else           { fidx = bh * 32 + (lane - 32);      foff = 1;  }
  }
  const int* flagp = gfl + fidx * 16;

#define ISSR(kk) { GLDC(gh[kk], rec + (kk) * 2048); }
#define ISSP(kk) { GLDC(ph[kk], pre + (kk) * 2048); }
#define MFR(kk, VC) { \
    half8 bl0 = wlo[(wv * 32 + 16 + (kk) * 2 + 0) * 64 + lane]; \
    half8 bl1 = wlo[(wv * 32 + 16 + (kk) * 2 + 1) * 64 + lane]; \
    waitv<VC>(); \
    acc0 = fma2(gh[kk], brhi[kk][0], bl0, acc0); \
    acc1 = fma2(gh[kk], brhi[kk][1], bl1, acc1); }
#define MFP(kk, VC) { \
    half8 bl0 = wlo[(wv * 32 + (kk) * 2 + 0) * 64 + lane]; \
    half8 bl1 = wlo[(wv * 32 + (kk) * 2 + 1) * 64 + lane]; \
    waitv<VC>(); \
    acc0 = fma2(ph[kk], bpre[kk][0], bl0, acc0); \
    acc1 = fma2(ph[kk], bpre[kk][1], bl1, acc1); }

  for (int t = 0; t < T_LEN; ++t) {
    // ---- L0: issue x loads before the poll (poll's flag-load wait drains them) ----
    f4 xa[8];
    if constexpr (L == 0) {
      const float* xr = x + ((size_t)(bh * 16 + l15) * T_LEN + t) * DIN;
#pragma unroll
      for (int kk = 0; kk < 4; ++kk) {
        int k = wv * 128 + kk * 32 + kb * 8;
        GLDP(xa[kk * 2],     (xr + k));
        GLDP(xa[kk * 2 + 1], (xr + k + 4));
      }
    }

    // ---- wave-lockstep guarded poll (each lane one dep) ----
    {
      const int thr = t + foff;
      unsigned gd = 0;
      while (LD_AG(flagp) < thr) {
        if (++gd > GUARD_CAP) break;
        __builtin_amdgcn_s_sleep(1);
      }
    }
    __builtin_amdgcn_sched_barrier(0);

    const char* rec = ringW + (size_t)(t & (RING - 1)) * 65536
                      + wv * 16384 + bh * 1024 + lane * 16;
    f4 acc0 = {0.f,0.f,0.f,0.f}, acc1 = acc0;
    half8 gh[8];

    if constexpr (L == 0) {
      // issue the WHOLE step's rec loads up front (8 in flight)
      ISSR(0); ISSR(1); ISSR(2); ISSR(3); ISSR(4); ISSR(5); ISSR(6); ISSR(7);
      // x-block (data already drained by the poll) overlaps the rec flight
#pragma unroll
      for (int kk = 0; kk < 4; ++kk) {
        half8 a0 = cvt8h(xa[kk * 2], xa[kk * 2 + 1]);
        half8 bl0 = wlo[(wv * 32 + kk * 2 + 0) * 64 + lane];
        half8 bl1 = wlo[(wv * 32 + kk * 2 + 1) * 64 + lane];
        acc0 = fma2(a0, bpre[kk][0], bl0, acc0);
        acc1 = fma2(a0, bpre[kk][1], bl1, acc1);
      }
      MFR(0, 7); MFR(1, 6); MFR(2, 5); MFR(3, 4);
      MFR(4, 3); MFR(5, 2); MFR(6, 1); MFR(7, 0);
    } else {
      // pre = layer0's h plane at parity (t+1) (== y0[t]); gated by gfl[L0] >= t+1
      const char* pre = h0ring + (size_t)((t + 1) & (RING - 1)) * 65536
                        + wv * 16384 + bh * 1024 + lane * 16;
      half8 ph[8];
      // 16 loads in flight: 8 rec (older) + 8 pre
      ISSR(0); ISSR(1); ISSR(2); ISSR(3); ISSR(4); ISSR(5); ISSR(6); ISSR(7);
      ISSP(0); ISSP(1); ISSP(2); ISSP(3); ISSP(4); ISSP(5); ISSP(6); ISSP(7);
      MFR(0, 15); MFR(1, 14); MFR(2, 13); MFR(3, 12);
      MFR(4, 11); MFR(5, 10); MFR(6, 9);  MFR(7, 8);
      MFP(0, 7); MFP(1, 6); MFP(2, 5); MFP(3, 4);
      MFP(4, 3); MFP(5, 2); MFP(6, 1); MFP(7, 0);
    }

    // ---- cross-wave K reduction via LDS (8 KB) ----
    *(f4*)&red[((wv * 2 + 0) * 64 + lane) * 4] = acc0;
    *(f4*)&red[((wv * 2 + 1) * 64 + lane) * 4] = acc1;
    __syncthreads();

    float vkeep[4];
    if (wv < 2) {
      f4 tot = *(const f4*)&red[((0 * 2 + wv) * 64 + lane) * 4];
      tot += *(const f4*)&red[((1 * 2 + wv) * 64 + lane) * 4];
      tot += *(const f4*)&red[((2 * 2 + wv) * 64 + lane) * 4];
      tot += *(const f4*)&red[((3 * 2 + wv) * 64 + lane) * 4];
      // C/D layout: col = lane&15, row = (lane>>4)*4 + reg  [m89]
#pragma unroll
      for (int rr = 0; rr < 4; ++rr) {
        const int bl = kb * 4 + rr;               // row 0..15 of this batch-half
        float v = tanh_fast(tot[rr] + biasv);
        vkeep[rr] = v;
        trh[bl * 36 + c_col] = h_bits(v);         // single f16 plane
      }
    }
    __syncthreads();   // tile ready

    // ---- wave 2: the ONE coalesced ring store (1 KB block) ----
    if (wv == 2) {
      const u16* srow = &trh[(lane & 15) * 36 + (lane >> 4) * 8];
      union { u64 q[2]; half8 s; } uu;
      uu.q[0] = ((const u64*)srow)[0];
      uu.q[1] = ((const u64*)srow)[1];
      char* d = ringW + (size_t)((t + 1) & (RING - 1)) * 65536
                + (size_t)(((cs * 2 + bh) * 64 + lane) * 16);
      GSTC(d, uu.s);
    }
    waitv<0>();        // wave 2 drains its ring store; others immediate
    __syncthreads();
    if (tid == 0) ST_AG(gfl + fid * 16, t + 1);   // publish BEFORE output stores

    // ---- outputs after publish (off the inter-WG critical path) ----
    if (wv < 2) {
      if constexpr (L == 1) {
#pragma unroll
        for (int rr = 0; rr < 4; ++rr) {
          const int brow = bh * 16 + kb * 4 + rr;
          float vo = __shfl_xor(vkeep[rr], 1, 64);
          if ((l15 & 1) == 0)
            *(float2*)&outy[((size_t)brow * T_LEN + t) * HID + e_i] = make_float2(vkeep[rr], vo);
        }
      }
      if (t == T_LEN - 1) {
#pragma unroll
        for (int rr = 0; rr < 4; ++rr) {
          const int brow = bh * 16 + kb * 4 + rr;
          outh[(size_t)L * 32768 + (size_t)brow * HID + e_i] = vkeep[rr];
        }
      }
    }
    // no end barrier needed (round-13-verified): next-step LDS writes are
    // separated from this step's reads by the barriers above.
  }
#undef ISSR
#undef ISSP
#undef MFR
#undef MFP
}

__global__ __launch_bounds__(256, 1)
void rnn_fused(const float* __restrict__ x,
               const float* __restrict__ Wih0, const float* __restrict__ Whh0,
               const float* __restrict__ bi0,  const float* __restrict__ bh0,
               const float* __restrict__ Wih1, const float* __restrict__ Whh1,
               const float* __restrict__ bi1,  const float* __restrict__ bh1,
               char* __restrict__ h0ring, char* __restrict__ h1ring,
               int* __restrict__ gfl,
               float* __restrict__ outy, float* __restrict__ outh) {
  __shared__ float red[8 * 64 * 4];        // 8 KB
  __shared__ u16   trh[16 * 36];           // 1.125 KB (f16 bits)
  __shared__ half8 wlo[4 * 32 * 64];       // 128 KB f16 residual weights
  const int wg = blockIdx.x;
  if (wg < 64)
    rnn_body<0>(x, Wih0, Whh0, bi0, bh0, h0ring, h1ring, gfl, outy, outh,
                red, trh, wlo, wg);
  else
    rnn_body<1>(x, Wih1, Whh1, bi1, bh1, h0ring, h1ring, gfl, outy, outh,
                red, trh, wlo, wg - 64);
}

extern "C" void kernel_launch(void* const* d_in, const int* in_sizes, int n_in,
                              void* d_out, int out_size, void* d_ws, size_t ws_size,
                              hipStream_t stream) {
  const float* x    = (const float*)d_in[0];
  const float* Wih0 = (const float*)d_in[1];
  const float* Whh0 = (const float*)d_in[2];
  const float* bi0  = (const float*)d_in[3];
  const float* bh0  = (const float*)d_in[4];
  const float* Wih1 = (const float*)d_in[5];
  const float* Whh1 = (const float*)d_in[6];
  const float* bi1  = (const float*)d_in[7];
  const float* bh1  = (const float*)d_in[8];

  float* outy = (float*)d_out;
  float* outh = outy + (size_t)32 * 1024 * 1024;   // [2][32][1024] tail

  char* ws = (char*)d_ws;
  char* h0ring = ws;                        // RING x 65536 B (single f16 plane)
  char* h1ring = ws + 524288;               // 512 KB
  int*  gfl    = (int*)(ws + 1048576);      // 128 flags x 64 B

  prep_kernel<<<64, 256, 0, stream>>>((unsigned int*)ws);
  rnn_fused<<<GRID, 256, 0, stream>>>(x, Wih0, Whh0, bi0, bh0,
                                      Wih1, Whh1, bi1, bh1,
                                      h0ring, h1ring, gfl, outy, outh);
}

// Round 15
// 2765.545 us; speedup vs baseline: 1.5177x; 1.0060x over previous
//
#include <hip/hip_runtime.h>

#define T_LEN 1024
#define DIN   512
#define HID   1024
#define GRID  128    // 64 WGs/layer: 32 col-slices x 2 batch-halves
#define RING  8
#define GUARD_CAP (1u << 18)   // poll watchdog: decay to fast wrong-answer, never hang

typedef __attribute__((ext_vector_type(8))) _Float16 half8;  // 8 x f16 (4 VGPRs)
typedef __attribute__((ext_vector_type(4))) float f4;
typedef unsigned long long u64;
typedef unsigned short u16;

#define LD_AG(p)    __hip_atomic_load((p),  __ATOMIC_RELAXED, __HIP_MEMORY_SCOPE_AGENT)
#define ST_AG(p, v) __hip_atomic_store((p), (v), __ATOMIC_RELAXED, __HIP_MEMORY_SCOPE_AGENT)

// L3-coherent 16B ops (proven round-6/10/13/14 path)
#define GLDC(dst, ptr) \
  asm volatile("global_load_dwordx4 %0, %1, off sc0 sc1" : "=v"(dst) : "v"(ptr))
#define GSTC(ptr, val) \
  asm volatile("global_store_dwordx4 %0, %1, off sc0 sc1" :: "v"(ptr), "v"(val) : "memory")
// plain cached 16B load (read-only x)
#define GLDP(dst, ptr) \
  asm volatile("global_load_dwordx4 %0, %1, off" : "=v"(dst) : "v"(ptr))

template<int N> __device__ __forceinline__ void waitv() {
  asm volatile("s_waitcnt vmcnt(%0)" :: "i"(N) : "memory");
  __builtin_amdgcn_sched_barrier(0);   // rule #18
}

__device__ __forceinline__ u16 h_bits(float f) {
  union { _Float16 h; u16 u; } v; v.h = (_Float16)f; return v.u;
}
// f32x8 -> f16x8 (RNE via v_cvt_f16_f32)
__device__ __forceinline__ half8 cvt8h(f4 a, f4 b) {
  half8 r;
#pragma unroll
  for (int j = 0; j < 4; ++j) { r[j] = (_Float16)a[j]; r[4 + j] = (_Float16)b[j]; }
  return r;
}
// f32x8 -> f16 hi + f16 residual (weights: combined error ~2^-22)
__device__ __forceinline__ void cvt8h_hl(f4 a, f4 b, half8& hi, half8& lo) {
  hi = cvt8h(a, b);
#pragma unroll
  for (int j = 0; j < 4; ++j) {
    lo[j]     = (_Float16)(a[j] - (float)hi[j]);
    lo[4 + j] = (_Float16)(b[j] - (float)hi[4 + j]);
  }
}
__device__ __forceinline__ float tanh_fast(float x) {
  float e = __expf(2.f * x);
  return 1.f - 2.f / (e + 1.f);
}
__device__ __forceinline__ f4 mfmah(half8 a, half8 b, f4 c) {
  return __builtin_amdgcn_mfma_f32_16x16x32_f16(a, b, c, 0, 0, 0);
}
// 2-term: a*(bh+bl)
__device__ __forceinline__ f4 fma2(half8 a, half8 bh, half8 bl, f4 c) {
  c = mfmah(a, bh, c);
  c = mfmah(a, bl, c);
  return c;
}

// zero parity-0 of both rings + 128 line-padded flags
// dword offsets: h0 par0 [0,16384) ; h1 par0 at 131072 ; flags at 262144 (2048 dw)
__global__ void prep_kernel(unsigned int* __restrict__ z) {
  int i = blockIdx.x * 256 + threadIdx.x;          // 64 blocks -> 16384 threads
  z[i] = 0u;                                       // h0 parity 0 (64 KB, f16 plane)
  z[131072 + i] = 0u;                              // h1 parity 0
  if (i < 2048) z[262144 + i] = 0u;                // flags (8 KB, 64B-padded)
}

// Persistent fused 2-layer RNN, batch-split — ROUND-14 BASE, per-wave producer gating.
// Ring block mapping (verified): byte wv*16384 + bh*1024 + kk*2048 -> block (cs'=wv*8+kk, bh),
// so each wave's data deps are exactly 8 producers. Lane budget per wave:
//   lanes 0-7  : the wave's 8 data producers, thr = t     (data gate, max-of-8)
//   lanes 8-31 : the other 24 same-layer same-bh peers, thr = t-6
//                (ring anti-dep: overwriting parity t+1 collides with reads at step
//                 t-7, implied complete by flag >= t-6.  Round-11's NaN = this gate
//                 missing: 8-wide data gate left 24 peers uncovered.)
//   lanes 32-63: cross-layer — L0: all 32 L1 same-bh thr t-4 (h0-ring pre-read anti-dep,
//                stricter than the exact t-7 bound, kept from round 13/14);
//                L1: lanes 32-39 = 8 pre producers (L0) thr t+1; lanes 40-63 spare
//                (duplicate rec producers thr t).
// Everything else byte-identical to round 14 (fp16 single-plane h, f16 hi/res weights,
// 64B-padded flags, full drain before publish, outputs after publish).
template<int L>
__device__ __forceinline__ void rnn_body(
    const float* __restrict__ x,
    const float* __restrict__ Wih, const float* __restrict__ Whh,
    const float* __restrict__ bias_i, const float* __restrict__ bias_h,
    char* __restrict__ h0ring, char* __restrict__ h1ring,
    int* __restrict__ gfl,
    float* __restrict__ outy, float* __restrict__ outh,
    float* red, u16* trh, half8* wlo, int wg) {
  const int fid = L * 64 + wg;        // global flag slot
  const int cs = wg & 31;
  const int bh = (wg >> 5) & 1;
  const int i_base = cs * 32;
  const int tid  = threadIdx.x;
  const int wv   = tid >> 6;
  const int lane = tid & 63;
  const int l15  = lane & 15;
  const int kb   = lane >> 4;

  constexpr int K1   = L ? HID : DIN;
  constexpr int NPRE = L ? 8 : 4;
  char* ringW = L ? h1ring : h0ring;

  // ---- hoist weights: f16 hi -> regs, f16 residual -> LDS ----
  half8 bpre[NPRE][2], brhi[8][2];
#pragma unroll
  for (int kk = 0; kk < NPRE; ++kk)
#pragma unroll
    for (int nf = 0; nf < 2; ++nf) {
      int k = wv * (K1 / 4) + kk * 32 + kb * 8;
      const float* sp = Wih + (size_t)(i_base + nf * 16 + l15) * K1 + k;
      half8 lo; cvt8h_hl(*(const f4*)sp, *(const f4*)(sp + 4), bpre[kk][nf], lo);
      wlo[(wv * 32 + kk * 2 + nf) * 64 + lane] = lo;
    }
#pragma unroll
  for (int kk = 0; kk < 8; ++kk)
#pragma unroll
    for (int nf = 0; nf < 2; ++nf) {
      int k = wv * 256 + kk * 32 + kb * 8;
      const float* sp = Whh + (size_t)(i_base + nf * 16 + l15) * HID + k;
      half8 lo; cvt8h_hl(*(const f4*)sp, *(const f4*)(sp + 4), brhi[kk][nf], lo);
      wlo[(wv * 32 + 16 + kk * 2 + nf) * 64 + lane] = lo;
    }
  __syncthreads();

  // epilogue constants (waves 0,1 finalize N-frag wv)
  const int e_i = i_base + (wv & 1) * 16 + l15;
  float biasv = 0.f;
  if (wv < 2) biasv = bias_i[e_i] + bias_h[e_i];
  const int c_col = (wv & 1) * 16 + l15;

  // ---- per-lane dependency mapping (per-wave producer gating; see header) ----
  int fidx, foff;
  if (lane < 8) {                                        // data producers (own layer)
    fidx = L * 64 + bh * 32 + wv * 8 + lane;             foff = 0;
  } else if (lane < 32) {                                // 24 remaining peers: ring anti-dep
    fidx = L * 64 + bh * 32 + ((wv * 8 + lane) & 31);    foff = -6;
  } else if (L == 0) {                                   // L0: h0-ring pre-read anti-dep (L1)
    fidx = 64 + bh * 32 + (lane - 32);                   foff = -4;
  } else if (lane < 40) {                                // L1: 8 pre producers (L0)
    fidx = bh * 32 + wv * 8 + (lane - 32);               foff = 1;
  } else {                                               // L1: spare — dup rec producers
    fidx = 64 + bh * 32 + wv * 8 + (lane & 7);           foff = 0;
  }
  const int* flagp = gfl + fidx * 16;

#define ISSR(kk) { GLDC(gh[kk], rec + (kk) * 2048); }
#define ISSP(kk) { GLDC(ph[kk], pre + (kk) * 2048); }
#define MFR(kk, VC) { \
    half8 bl0 = wlo[(wv * 32 + 16 + (kk) * 2 + 0) * 64 + lane]; \
    half8 bl1 = wlo[(wv * 32 + 16 + (kk) * 2 + 1) * 64 + lane]; \
    waitv<VC>(); \
    acc0 = fma2(gh[kk], brhi[kk][0], bl0, acc0); \
    acc1 = fma2(gh[kk], brhi[kk][1], bl1, acc1); }
#define MFP(kk, VC) { \
    half8 bl0 = wlo[(wv * 32 + (kk) * 2 + 0) * 64 + lane]; \
    half8 bl1 = wlo[(wv * 32 + (kk) * 2 + 1) * 64 + lane]; \
    waitv<VC>(); \
    acc0 = fma2(ph[kk], bpre[kk][0], bl0, acc0); \
    acc1 = fma2(ph[kk], bpre[kk][1], bl1, acc1); }

  for (int t = 0; t < T_LEN; ++t) {
    // ---- L0: issue x loads before the poll (poll's flag-load wait drains them) ----
    f4 xa[8];
    if constexpr (L == 0) {
      const float* xr = x + ((size_t)(bh * 16 + l15) * T_LEN + t) * DIN;
#pragma unroll
      for (int kk = 0; kk < 4; ++kk) {
        int k = wv * 128 + kk * 32 + kb * 8;
        GLDP(xa[kk * 2],     (xr + k));
        GLDP(xa[kk * 2 + 1], (xr + k + 4));
      }
    }

    // ---- wave-lockstep guarded poll (each lane one dep) ----
    {
      const int thr = t + foff;
      unsigned gd = 0;
      while (LD_AG(flagp) < thr) {
        if (++gd > GUARD_CAP) break;
        __builtin_amdgcn_s_sleep(1);
      }
    }
    __builtin_amdgcn_sched_barrier(0);

    const char* rec = ringW + (size_t)(t & (RING - 1)) * 65536
                      + wv * 16384 + bh * 1024 + lane * 16;
    f4 acc0 = {0.f,0.f,0.f,0.f}, acc1 = acc0;
    half8 gh[8];

    if constexpr (L == 0) {
      // issue the WHOLE step's rec loads up front (8 in flight)
      ISSR(0); ISSR(1); ISSR(2); ISSR(3); ISSR(4); ISSR(5); ISSR(6); ISSR(7);
      // x-block (data already drained by the poll) overlaps the rec flight
#pragma unroll
      for (int kk = 0; kk < 4; ++kk) {
        half8 a0 = cvt8h(xa[kk * 2], xa[kk * 2 + 1]);
        half8 bl0 = wlo[(wv * 32 + kk * 2 + 0) * 64 + lane];
        half8 bl1 = wlo[(wv * 32 + kk * 2 + 1) * 64 + lane];
        acc0 = fma2(a0, bpre[kk][0], bl0, acc0);
        acc1 = fma2(a0, bpre[kk][1], bl1, acc1);
      }
      MFR(0, 7); MFR(1, 6); MFR(2, 5); MFR(3, 4);
      MFR(4, 3); MFR(5, 2); MFR(6, 1); MFR(7, 0);
    } else {
      // pre = layer0's h plane at parity (t+1) (== y0[t]); gated by gfl[L0] >= t+1
      const char* pre = h0ring + (size_t)((t + 1) & (RING - 1)) * 65536
                        + wv * 16384 + bh * 1024 + lane * 16;
      half8 ph[8];
      // 16 loads in flight: 8 rec (older) + 8 pre
      ISSR(0); ISSR(1); ISSR(2); ISSR(3); ISSR(4); ISSR(5); ISSR(6); ISSR(7);
      ISSP(0); ISSP(1); ISSP(2); ISSP(3); ISSP(4); ISSP(5); ISSP(6); ISSP(7);
      MFR(0, 15); MFR(1, 14); MFR(2, 13); MFR(3, 12);
      MFR(4, 11); MFR(5, 10); MFR(6, 9);  MFR(7, 8);
      MFP(0, 7); MFP(1, 6); MFP(2, 5); MFP(3, 4);
      MFP(4, 3); MFP(5, 2); MFP(6, 1); MFP(7, 0);
    }

    // ---- cross-wave K reduction via LDS (8 KB) ----
    *(f4*)&red[((wv * 2 + 0) * 64 + lane) * 4] = acc0;
    *(f4*)&red[((wv * 2 + 1) * 64 + lane) * 4] = acc1;
    __syncthreads();

    float vkeep[4];
    if (wv < 2) {
      f4 tot = *(const f4*)&red[((0 * 2 + wv) * 64 + lane) * 4];
      tot += *(const f4*)&red[((1 * 2 + wv) * 64 + lane) * 4];
      tot += *(const f4*)&red[((2 * 2 + wv) * 64 + lane) * 4];
      tot += *(const f4*)&red[((3 * 2 + wv) * 64 + lane) * 4];
      // C/D layout: col = lane&15, row = (lane>>4)*4 + reg  [m89]
#pragma unroll
      for (int rr = 0; rr < 4; ++rr) {
        const int bl = kb * 4 + rr;               // row 0..15 of this batch-half
        float v = tanh_fast(tot[rr] + biasv);
        vkeep[rr] = v;
        trh[bl * 36 + c_col] = h_bits(v);         // single f16 plane
      }
    }
    __syncthreads();   // tile ready

    // ---- wave 2: the ONE coalesced ring store (1 KB block) ----
    if (wv == 2) {
      const u16* srow = &trh[(lane & 15) * 36 + (lane >> 4) * 8];
      union { u64 q[2]; half8 s; } uu;
      uu.q[0] = ((const u64*)srow)[0];
      uu.q[1] = ((const u64*)srow)[1];
      char* d = ringW + (size_t)((t + 1) & (RING - 1)) * 65536
                + (size_t)(((cs * 2 + bh) * 64 + lane) * 16);
      GSTC(d, uu.s);
    }
    waitv<0>();        // wave 2 drains its ring store; others immediate
    __syncthreads();
    if (tid == 0) ST_AG(gfl + fid * 16, t + 1);   // publish BEFORE output stores

    // ---- outputs after publish (off the inter-WG critical path) ----
    if (wv < 2) {
      if constexpr (L == 1) {
#pragma unroll
        for (int rr = 0; rr < 4; ++rr) {
          const int brow = bh * 16 + kb * 4 + rr;
          float vo = __shfl_xor(vkeep[rr], 1, 64);
          if ((l15 & 1) == 0)
            *(float2*)&outy[((size_t)brow * T_LEN + t) * HID + e_i] = make_float2(vkeep[rr], vo);
        }
      }
      if (t == T_LEN - 1) {
#pragma unroll
        for (int rr = 0; rr < 4; ++rr) {
          const int brow = bh * 16 + kb * 4 + rr;
          outh[(size_t)L * 32768 + (size_t)brow * HID + e_i] = vkeep[rr];
        }
      }
    }
    // no end barrier needed (round-13/14-verified): next-step LDS writes are
    // separated from this step's reads by the barriers above.
  }
#undef ISSR
#undef ISSP
#undef MFR
#undef MFP
}

__global__ __launch_bounds__(256, 1)
void rnn_fused(const float* __restrict__ x,
               const float* __restrict__ Wih0, const float* __restrict__ Whh0,
               const float* __restrict__ bi0,  const float* __restrict__ bh0,
               const float* __restrict__ Wih1, const float* __restrict__ Whh1,
               const float* __restrict__ bi1,  const float* __restrict__ bh1,
               char* __restrict__ h0ring, char* __restrict__ h1ring,
               int* __restrict__ gfl,
               float* __restrict__ outy, float* __restrict__ outh) {
  __shared__ float red[8 * 64 * 4];        // 8 KB
  __shared__ u16   trh[16 * 36];           // 1.125 KB (f16 bits)
  __shared__ half8 wlo[4 * 32 * 64];       // 128 KB f16 residual weights
  const int wg = blockIdx.x;
  if (wg < 64)
    rnn_body<0>(x, Wih0, Whh0, bi0, bh0, h0ring, h1ring, gfl, outy, outh,
                red, trh, wlo, wg);
  else
    rnn_body<1>(x, Wih1, Whh1, bi1, bh1, h0ring, h1ring, gfl, outy, outh,
                red, trh, wlo, wg - 64);
}

extern "C" void kernel_launch(void* const* d_in, const int* in_sizes, int n_in,
                              void* d_out, int out_size, void* d_ws, size_t ws_size,
                              hipStream_t stream) {
  const float* x    = (const float*)d_in[0];
  const float* Wih0 = (const float*)d_in[1];
  const float* Whh0 = (const float*)d_in[2];
  const float* bi0  = (const float*)d_in[3];
  const float* bh0  = (const float*)d_in[4];
  const float* Wih1 = (const float*)d_in[5];
  const float* Whh1 = (const float*)d_in[6];
  const float* bi1  = (const float*)d_in[7];
  const float* bh1  = (const float*)d_in[8];

  float* outy = (float*)d_out;
  float* outh = outy + (size_t)32 * 1024 * 1024;   // [2][32][1024] tail

  char* ws = (char*)d_ws;
  char* h0ring = ws;                        // RING x 65536 B (single f16 plane)
  char* h1ring = ws + 524288;               // 512 KB
  int*  gfl    = (int*)(ws + 1048576);      // 128 flags x 64 B

  prep_kernel<<<64, 256, 0, stream>>>((unsigned int*)ws);
  rnn_fused<<<GRID, 256, 0, stream>>>(x, Wih0, Whh0, bi0, bh0,
                                      Wih1, Whh1, bi1, bh1,
                                      h0ring, h1ring, gfl, outy, outh);
}